// Round 13
// baseline (63.336 us; speedup 1.0000x reference)
//
#include <hip/hip_runtime.h>
#include <math.h>

typedef _Float16 f16;
typedef f16 f16x8 __attribute__((ext_vector_type(8)));
typedef float f32x16 __attribute__((ext_vector_type(16)));

static constexpr int Bn = 16;
static constexpr int Kn = 4096;
static constexpr int MGRID = 512;       // rg(32) x b(16)
static constexpr int NPSUM = 1024;      // old 1024-slot psum layout
static constexpr float WBIG = 49152.0f; // exact in fp16
static constexpr float QMIN0 = 3e37f;

// Round-13: single-pass dual-extraction. The distance matrix was computed
// TWICE (once per chamfer direction); this kernel computes it once and
// extracts BOTH mins per tile: lane-local col-mins (p2t, via qpart
// partials) and running row-mins (t2p, via one end-of-loop butterfly).
// Total MFMAs halve: 524288 -> 262144 (512/SIMD -> 256/SIMD) — the one
// axis the R5-R12 elimination matrix never moved. VALU grows ~1.75x,
// which R11 measured as free.
//  - p2t: bitwise-identical to old dir0 (same A/B fragments for valid
//    points -> identical d2 multiset -> identical min; invalid preds
//    masked by mask-test instead of -WBIG marking, both exactly 0.0).
//  - t2p: extracted from the transposed orientation; product multiset
//    identical but k-slot order swapped -> d2 may differ ~1 ulp (absmax
//    ~1e-7 instead of 0.0).
//  - MFMAs issued in pairs (d0/d1, d2/d3) to cap register liveness ~175
//    < 256 cap at (256,2). Tripwire: WRITE_SIZE balloon = spill.
__global__ __launch_bounds__(256, 2) void chamfer_dual_kernel(
        const float* __restrict__ pred, const float* __restrict__ target,
        const int* __restrict__ mask,
        float* __restrict__ qpart, float* __restrict__ psum,
        unsigned int* __restrict__ cnt4) {
    int bid = blockIdx.x;
    int lin = (bid & 7) * 64 + (bid >> 3);    // XCD-contiguous logical id
    int rg = lin & 31;                        // target ref group (128 pts)
    int b  = (lin >> 5) & 15;

    int tid = threadIdx.x;
    int w = tid >> 6, l = tid & 63;
    int r = l & 31, g = l >> 5;

    const f16 one = (f16)1.0f, zero = (f16)0.0f;

    // opaque zero C-operand (runtime value IS 0, provenance hidden)
    float zf;
    asm volatile("v_mov_b32 %0, 0" : "=v"(zf));
    f32x16 cz;
    #pragma unroll
    for (int i = 0; i < 16; ++i) cz[i] = zf;

    // ---- 4 A fragments from target ref tiles rg*4+rr (bit-identical to
    // the old dir0 A side: valid -> w_t hi/lo, invalid -> +WBIG) ----
    f16x8 a0, a1, a2, a3;
#define BUILD_A(rr, dst) { \
    int idx = b * 4096 + (rg * 4 + rr) * 32 + r; \
    bool v = mask[idx] != 0; \
    float x = target[idx*3+0], y = target[idx*3+1], z = target[idx*3+2]; \
    if (!v) { x = 0.0f; y = 0.0f; z = 0.0f; } \
    float wv = fmaf(x, x, fmaf(y, y, z * z)); \
    f16 xh = (f16)x, yh = (f16)y, zh = (f16)z; \
    f16 xl = (f16)(x-(float)xh), yl = (f16)(y-(float)yh), zl = (f16)(z-(float)zh); \
    f16 m2xh = (f16)(-2.0f*(float)xh), m2xl = (f16)(-2.0f*(float)xl); \
    f16 m2yh = (f16)(-2.0f*(float)yh), m2yl = (f16)(-2.0f*(float)yl); \
    f16 m2zh = (f16)(-2.0f*(float)zh), m2zl = (f16)(-2.0f*(float)zl); \
    f16 whA, wlA; \
    if (v) { f16 wh = (f16)wv; whA = wh; wlA = (f16)(wv-(float)wh); } \
    else   { whA = (f16)WBIG; wlA = zero; } \
    f16x8 alo = {m2xh, m2xh, m2xl, m2yh, m2yh, m2yl, m2zh, m2zh}; \
    f16x8 ahi = {m2zl, whA, wlA, one, one, zero, zero, zero}; \
    dst = g ? ahi : alo; }
    BUILD_A(0, a0) BUILD_A(1, a1) BUILD_A(2, a2) BUILD_A(3, a3)
#undef BUILD_A

    // running t2p row-mins, one f32x16 per ref tile (static indices only)
    f32x16 rm0, rm1, rm2, rm3;
    #pragma unroll
    for (int i = 0; i < 16; ++i) {
        rm0[i] = QMIN0; rm1[i] = QMIN0; rm2[i] = QMIN0; rm3[i] = QMIN0;
    }

    size_t qbase = (size_t)(b * 32 + rg) * 4096;
    for (int s = 0; s < 32; ++s) {
        int qt = w + 4 * s;               // pred query tile (4 waves cover 128)
        // B fragment from pred (old dir0 B side, but invalid -> +WBIG so
        // invalid preds never win the t2p row-min; p2t invalids are
        // masked in p2t_kernel instead -> same exact 0.0 contribution)
        int idx = b * 4096 + qt * 32 + r;
        bool v = mask[idx] != 0;
        float x = pred[idx*3+0], y = pred[idx*3+1], z = pred[idx*3+2];
        if (!v) { x = 0.0f; y = 0.0f; z = 0.0f; }
        float wv = fmaf(x, x, fmaf(y, y, z * z));
        f16 xh = (f16)x, yh = (f16)y, zh = (f16)z;
        f16 xl = (f16)(x-(float)xh), yl = (f16)(y-(float)yh), zl = (f16)(z-(float)zh);
        f16 whB, wlB;
        if (v) { f16 wh = (f16)wv; whB = wh; wlB = (f16)(wv-(float)wh); }
        else   { whB = (f16)WBIG; wlB = zero; }
        f16x8 blo = {xh, xl, xh, yh, yl, yh, zh, zl};
        f16x8 bhi = {zh, one, one, whB, wlB, zero, zero, zero};
        f16x8 bf = g ? bhi : blo;

        // pair 1: ref tiles 0,1
        float qv[16];
        {
            f32x16 d0 = __builtin_amdgcn_mfma_f32_32x32x16_f16(a0, bf, cz, 0, 0, 0);
            f32x16 d1 = __builtin_amdgcn_mfma_f32_32x32x16_f16(a1, bf, cz, 0, 0, 0);
            #pragma unroll
            for (int i = 0; i < 16; ++i) {
                rm0[i] = fminf(rm0[i], d0[i]);
                rm1[i] = fminf(rm1[i], d1[i]);
                qv[i] = fminf(d0[i], d1[i]);
            }
        }
        // pair 2: ref tiles 2,3
        {
            f32x16 d2 = __builtin_amdgcn_mfma_f32_32x32x16_f16(a2, bf, cz, 0, 0, 0);
            f32x16 d3 = __builtin_amdgcn_mfma_f32_32x32x16_f16(a3, bf, cz, 0, 0, 0);
            #pragma unroll
            for (int i = 0; i < 16; ++i) {
                rm2[i] = fminf(rm2[i], d2[i]);
                rm3[i] = fminf(rm3[i], d3[i]);
                qv[i] = fminf(qv[i], fminf(d2[i], d3[i]));
            }
        }
        // p2t partial: min over the block's 128 target rows for query col
        float ql = qv[0];
        #pragma unroll
        for (int i = 1; i < 16; ++i) ql = fminf(ql, qv[i]);
        ql = fminf(ql, __shfl_xor(ql, 32, 64));   // combine row halves
        if (l < 32) qpart[qbase + (size_t)qt * 32 + l] = ql;
    }

    // butterfly: min across the 32 query-col lanes (per row-half group)
    #pragma unroll
    for (int st = 1; st < 32; st <<= 1) {
        #pragma unroll
        for (int i = 0; i < 16; ++i) {
            rm0[i] = fminf(rm0[i], __shfl_xor(rm0[i], st, 64));
            rm1[i] = fminf(rm1[i], __shfl_xor(rm1[i], st, 64));
            rm2[i] = fminf(rm2[i], __shfl_xor(rm2[i], st, 64));
            rm3[i] = fminf(rm3[i], __shfl_xor(rm3[i], st, 64));
        }
    }

    // per wave: full-query min for its 4 ref tiles' 32 rows -> LDS
    __shared__ float comb2[4][4][32];
    if (r == 0) {
        #pragma unroll
        for (int i = 0; i < 16; ++i) {
            int row = (i & 3) + 8 * (i >> 2) + 4 * g;
            comb2[w][0][row] = rm0[i];
            comb2[w][1][row] = rm1[i];
            comb2[w][2][row] = rm2[i];
            comb2[w][3][row] = rm3[i];
        }
    }
    __syncthreads();

    // t2p reduction: reconstruct old dir1 block (qg1=rg, b) in the exact
    // old thread/shuffle order -> psum slot 512 + b*32 + rg.
    float contrib = 0.0f;
    bool validq = false;
    if (tid < 128) {
        int qt = tid >> 5, c = tid & 31;
        float m = fminf(fminf(comb2[0][qt][c], comb2[1][qt][c]),
                        fminf(comb2[2][qt][c], comb2[3][qt][c]));
        validq = mask[b * 4096 + rg * 128 + tid] != 0;
        contrib = validq ? sqrtf(fmaxf(m, 1e-12f)) : 0.0f;
    }
    // cnt4: same per-64-point popcounts as old prep (waves 0,1 cover the
    // block's 128 points; each (b,rg) owns 2 disjoint slots)
    unsigned long long mb = __ballot(validq);
    if ((tid & 63) == 0 && w < 2)
        cnt4[b * 64 + rg * 2 + w] = (unsigned int)__popcll(mb);
    for (int off = 32; off; off >>= 1)
        contrib += __shfl_down(contrib, off, 64);
    __shared__ float ps[4];
    if ((tid & 63) == 0) ps[tid >> 6] = contrib;
    __syncthreads();
    if (tid == 0)
        psum[512 + b * 32 + rg] = ps[0] + ps[1] + ps[2] + ps[3];
}

// p2t finish: old dir0 block (qg,b) -> fold the 32 rg-partials (min over
// the identical 4096-value set as the old comb reduction -> bitwise-same
// m), mask invalid preds (exact 0.0, same as old -WBIG test), then the
// exact old shuffle order -> psum slot b*32 + qg.
__global__ __launch_bounds__(256) void p2t_kernel(
        const float* __restrict__ qpart, const int* __restrict__ mask,
        float* __restrict__ psum) {
    int bid = blockIdx.x;
    int qg = bid & 31, b = bid >> 5;
    int tid = threadIdx.x;
    float contrib = 0.0f;
    if (tid < 128) {
        int qp = qg * 128 + tid;
        float m = QMIN0;
        #pragma unroll 8
        for (int rg = 0; rg < 32; ++rg)
            m = fminf(m, qpart[(size_t)(b * 32 + rg) * 4096 + qp]);
        bool v = mask[b * 4096 + qp] != 0;
        contrib = v ? sqrtf(fmaxf(m, 1e-12f)) : 0.0f;
    }
    for (int off = 32; off; off >>= 1)
        contrib += __shfl_down(contrib, off, 64);
    __shared__ float ps[4];
    if ((tid & 63) == 0) ps[tid >> 6] = contrib;
    __syncthreads();
    if (tid == 0)
        psum[b * 32 + qg] = ps[0] + ps[1] + ps[2] + ps[3];
}

__global__ __launch_bounds__(256) void final_kernel(
        const unsigned int* __restrict__ cnt4, const float* __restrict__ psum,
        float* __restrict__ out) {
    int t = threadIdx.x;
    unsigned int c = 0;
    float s = 0.0f;
    #pragma unroll
    for (int i = 0; i < 4; ++i) {
        c += cnt4[t + 256 * i];
        s += psum[t + 256 * i];
    }
    for (int off = 32; off; off >>= 1) {
        c += __shfl_down(c, off, 64);
        s += __shfl_down(s, off, 64);
    }
    __shared__ unsigned int cs[4];
    __shared__ float ss[4];
    if ((t & 63) == 0) { cs[t >> 6] = c; ss[t >> 6] = s; }
    __syncthreads();
    if (t == 0) {
        unsigned int C = cs[0] + cs[1] + cs[2] + cs[3];
        float S = ss[0] + ss[1] + ss[2] + ss[3];
        out[0] = S * 0.5f / ((float)C + 1e-8f);
    }
}

extern "C" void kernel_launch(void* const* d_in, const int* in_sizes, int n_in,
                              void* d_out, int out_size, void* d_ws, size_t ws_size,
                              hipStream_t stream) {
    const float* pred = (const float*)d_in[0];
    const float* target = (const float*)d_in[1];
    const int* mask = (const int*)d_in[2];
    float* out = (float*)d_out;

    // ws: [qpart 8M | psum 4K | cnt4 4K]
    char* ws = (char*)d_ws;
    float* qpart = (float*)ws;
    float* psum = (float*)(ws + (size_t)512 * 4096 * sizeof(float));
    unsigned int* cnt4 = (unsigned int*)((char*)psum + NPSUM * sizeof(float));

    chamfer_dual_kernel<<<MGRID, 256, 0, stream>>>(
        pred, target, mask, qpart, psum, cnt4);
    p2t_kernel<<<MGRID, 256, 0, stream>>>(qpart, mask, psum);
    final_kernel<<<1, 256, 0, stream>>>(cnt4, psum, out);
}

// Round 14
// 27.677 us; speedup vs baseline: 2.2884x; 2.2884x over previous
//
#include <hip/hip_runtime.h>
#include <math.h>

typedef _Float16 f16;
typedef f16 f16x8 __attribute__((ext_vector_type(8)));
typedef float f32x16 __attribute__((ext_vector_type(16)));

static constexpr int Bn = 16;
static constexpr int Kn = 4096;
static constexpr int NPTS = Bn * Kn;    // 65536
static constexpr int MGRID = 512;       // qg8(16) x b(16) x dir(2)
static constexpr int NPSUM = 1024;      // old 1024-slot psum layout
static constexpr float WBIG = 49152.0f; // exact in fp16
static constexpr float QMIN0 = 3e37f;

// Round-14: R11 VERBATIM (best, 28.0) + ONE line per MFMA:
//     asm volatile("" : "+v"(d));
// forcing the MFMA result tuple into VGPRs. Rationale: R13's PMC showed a
// ~3x multiplier between source-level VALU ops and measured VALU-busy —
// the signature of accumulators living in AGPRs (every consume = 
// v_accvgpr_read + op [+ write]). If R11's d (f32x16, MFMA's native AGPR
// destination) is AGPR-allocated, the 8-min3 drain per tile carries 16
// hidden accvgpr_reads = 2x the visible VALU (~6-7 us/SIMD over the
// kernel) — and explains R2's VALU-busy ~= MFMA-busy despite min3 work
// being half that, plus why scheduling changes (R9/R12) were null (cost
// is instruction COUNT, not order). The "+v" pin makes the coalescer
// allocate the MFMA dst as VGPRs (legal: gfx950 unified file, isa §10);
// hazards still compiler-managed (builtin untouched). If d was already
// VGPR this is a no-op. Bitwise-identical numerics.
__global__ __launch_bounds__(256, 2) void chamfer_fused_kernel(
        const float* __restrict__ pred, const float* __restrict__ target,
        const int* __restrict__ mask,
        float* __restrict__ psum, unsigned int* __restrict__ cnt4) {
    int bid = blockIdx.x;
    int lin = (bid & 7) * 64 + (bid >> 3);    // XCD-contiguous logical id
    int qg8 = lin & 15; lin >>= 4;            // qg8(16) fastest, b(16), dir(2)
    int b   = lin & 15; lin >>= 4;
    int dir = lin;                            // 0: queries=pred, refs=target
    int j0 = dir * 512 + b * 32 + qg8 * 2;    // old logical psum slots
    int j1 = j0 + 1;

    const float* __restrict__ Araw = dir ? pred : target;  // refs
    const float* __restrict__ Braw = dir ? target : pred;  // queries

    int tid = threadIdx.x;
    int w = tid >> 6, l = tid & 63;
    int r = l & 31, g = l >> 5;

    __shared__ float comb[4][8][64];

    // opaque zero C-operand: runtime value IS 0, provenance hidden.
    float zf;
    asm volatile("v_mov_b32 %0, 0" : "=v"(zf));
    f32x16 cz;
    #pragma unroll
    for (int i = 0; i < 16; ++i) cz[i] = zf;

    const f16 one = (f16)1.0f, zero = (f16)0.0f;

    // ---- B fragments for this block's 8 query tiles (same bit-values as
    // old prep's B slots: B = {xh,xl,xh,yh,yl,yh,zh,zl | zh,1,1,whB,wlB,0,0,0})
    f16x8 bq[8];
    unsigned int bcnt[8];
    #pragma unroll
    for (int qt = 0; qt < 8; ++qt) {
        int idx = b * 4096 + (qg8 * 8 + qt) * 32 + r;
        bool valid = mask[idx] != 0;
        float x = Braw[idx * 3 + 0], y = Braw[idx * 3 + 1], z = Braw[idx * 3 + 2];
        if (!valid) { x = 0.0f; y = 0.0f; z = 0.0f; }
        float wv = fmaf(x, x, fmaf(y, y, z * z));
        f16 xh = (f16)x, yh = (f16)y, zh = (f16)z;
        f16 xl = (f16)(x - (float)xh), yl = (f16)(y - (float)yh), zl = (f16)(z - (float)zh);
        f16 whB, wlB;
        if (valid) { f16 wh = (f16)wv; whB = wh; wlB = (f16)(wv - (float)wh); }
        else       { whB = (f16)(-WBIG); wlB = zero; }
        f16x8 blo = {xh, xl, xh, yh, yl, yh, zh, zl};
        f16x8 bhi = {zh, one, one, whB, wlB, zero, zero, zero};
        bq[qt] = g ? bhi : blo;
        // lanes r and r+32 hold the same point -> popcll is 2x the count
        unsigned long long mb = __ballot(valid);
        bcnt[qt] = (unsigned int)__popcll(mb) >> 1;
    }
    // dir=0 blocks own cnt4 slots b*64 + qg8*4 + m (64 consecutive points
    // each = qt pair (2m,2m+1)) — same values as old prep's ballots.
    if (dir == 0 && w == 0 && l == 0) {
        #pragma unroll
        for (int m = 0; m < 4; ++m)
            cnt4[b * 64 + qg8 * 4 + m] = bcnt[2 * m] + bcnt[2 * m + 1];
    }

    float qA[8], qB[8];
    #pragma unroll
    for (int qt = 0; qt < 8; ++qt) { qA[qt] = QMIN0; qB[qt] = QMIN0; }

    // wave w covers ref tiles rt = w + 4t, t = 0..31 (R7's exact order).
    #pragma unroll 4
    for (int t = 0; t < 32; ++t) {
        int idxA = b * 4096 + (w + 4 * t) * 32 + r;
        bool valid = mask[idxA] != 0;
        float x = Araw[idxA * 3 + 0], y = Araw[idxA * 3 + 1], z = Araw[idxA * 3 + 2];
        if (!valid) { x = 0.0f; y = 0.0f; z = 0.0f; }
        // A slots (bit-identical to old prep):
        // A = {m2xh,m2xh,m2xl,m2yh,m2yh,m2yl,m2zh,m2zh | m2zl,whA,wlA,1,1,0,0,0}
        float wv = fmaf(x, x, fmaf(y, y, z * z));
        f16 xh = (f16)x, yh = (f16)y, zh = (f16)z;
        f16 xl = (f16)(x - (float)xh), yl = (f16)(y - (float)yh), zl = (f16)(z - (float)zh);
        f16 m2xh = (f16)(-2.0f * (float)xh), m2xl = (f16)(-2.0f * (float)xl);
        f16 m2yh = (f16)(-2.0f * (float)yh), m2yl = (f16)(-2.0f * (float)yl);
        f16 m2zh = (f16)(-2.0f * (float)zh), m2zl = (f16)(-2.0f * (float)zl);
        f16 whA, wlA;
        if (valid) { f16 wh = (f16)wv; whA = wh; wlA = (f16)(wv - (float)wh); }
        else       { whA = (f16)WBIG; wlA = zero; }
        f16x8 alo = {m2xh, m2xh, m2xl, m2yh, m2yh, m2yl, m2zh, m2zh};
        f16x8 ahi = {m2zl, whA, wlA, one, one, zero, zero, zero};
        f16x8 a = g ? ahi : alo;

        #pragma unroll
        for (int qt = 0; qt < 8; ++qt) {
            f32x16 d = __builtin_amdgcn_mfma_f32_32x32x16_f16(a, bq[qt], cz, 0, 0, 0);
            asm volatile("" : "+v"(d));   // pin MFMA dst to VGPRs (no AGPR reads)
            #pragma unroll
            for (int i = 0; i < 4; ++i) {
                qA[qt] = fminf(fminf(qA[qt], d[4 * i + 0]), d[4 * i + 1]);  // -> v_min3
                qB[qt] = fminf(fminf(qB[qt], d[4 * i + 2]), d[4 * i + 3]);  // -> v_min3
            }
        }
    }

    #pragma unroll
    for (int qt = 0; qt < 8; ++qt) comb[w][qt][l] = fminf(qA[qt], qB[qt]);
    __syncthreads();

    // Two independent reductions, each the EXACT old-block computation.
    float c0 = 0.0f, c1 = 0.0f;
    if (tid < 128) {
        int qt = tid >> 5, c = tid & 31;
        float m0 = QMIN0, m1 = QMIN0;
        #pragma unroll
        for (int ww = 0; ww < 4; ++ww)
            #pragma unroll
            for (int h = 0; h < 2; ++h) {
                m0 = fminf(m0, comb[ww][qt][h * 32 + c]);
                m1 = fminf(m1, comb[ww][qt + 4][h * 32 + c]);
            }
        // m < -1e4 marks an invalid query (w_q = -WBIG); contributes 0
        c0 = (m0 < -1e4f) ? 0.0f : sqrtf(fmaxf(m0, 1e-12f));
        c1 = (m1 < -1e4f) ? 0.0f : sqrtf(fmaxf(m1, 1e-12f));
    }
    for (int off = 32; off; off >>= 1) {
        c0 += __shfl_down(c0, off, 64);
        c1 += __shfl_down(c1, off, 64);
    }
    __shared__ float ps0[4], ps1[4];
    if ((tid & 63) == 0) { ps0[tid >> 6] = c0; ps1[tid >> 6] = c1; }
    __syncthreads();
    if (tid == 0) {
        psum[j0] = ps0[0] + ps0[1] + ps0[2] + ps0[3];
        psum[j1] = ps1[0] + ps1[1] + ps1[2] + ps1[3];
    }
}

__global__ __launch_bounds__(256) void final_kernel(
        const unsigned int* __restrict__ cnt4, const float* __restrict__ psum,
        float* __restrict__ out) {
    int t = threadIdx.x;
    unsigned int c = 0;
    float s = 0.0f;
    #pragma unroll
    for (int i = 0; i < 4; ++i) {
        c += cnt4[t + 256 * i];
        s += psum[t + 256 * i];
    }
    for (int off = 32; off; off >>= 1) {
        c += __shfl_down(c, off, 64);
        s += __shfl_down(s, off, 64);
    }
    __shared__ unsigned int cs[4];
    __shared__ float ss[4];
    if ((t & 63) == 0) { cs[t >> 6] = c; ss[t >> 6] = s; }
    __syncthreads();
    if (t == 0) {
        unsigned int C = cs[0] + cs[1] + cs[2] + cs[3];
        float S = ss[0] + ss[1] + ss[2] + ss[3];
        out[0] = S * 0.5f / ((float)C + 1e-8f);
    }
}

extern "C" void kernel_launch(void* const* d_in, const int* in_sizes, int n_in,
                              void* d_out, int out_size, void* d_ws, size_t ws_size,
                              hipStream_t stream) {
    const float* pred = (const float*)d_in[0];
    const float* target = (const float*)d_in[1];
    const int* mask = (const int*)d_in[2];
    float* out = (float*)d_out;

    // ws: [psum 4K | cnt4 4K]
    char* ws = (char*)d_ws;
    float* psum = (float*)ws;
    unsigned int* cnt4 = (unsigned int*)(ws + NPSUM * sizeof(float));

    chamfer_fused_kernel<<<MGRID, 256, 0, stream>>>(
        pred, target, mask, psum, cnt4);
    final_kernel<<<1, 256, 0, stream>>>(cnt4, psum, out);
}